// Round 1
// baseline (69.251 us; speedup 1.0000x reference)
//
#include <hip/hip_runtime.h>

#define N       8192   // 8*32*32  (DEPTH=8, LENGTH=32, WIDTH=32)
#define NCLS    8
#define ROWS_PB 8                  // one wave (64 lanes) per row, 8 rows per block
#define GRID    (N / ROWS_PB)      // 1024 blocks
#define NCELL   784                // block window union: 7x * 7y * 16z cells

// One WAVE per row i. Lanes cover the exact significant neighborhood:
// y in [yi-3,yi+3] (7 rows) x z in [zi-4,zi+4] (9 cols), x in [xi-3,xi+3]
// (7, clamp-shifted windows always inside the volume). Dropped terms have
// weight <= exp(-16) ~ 1e-7; every computed term is exact.
//
// NEW vs previous round: the 8 rows of a block share (xi, yi) and a 16-wide
// z-range, so the union of all their windows is 7x*7y*16z = 784 cells.
// We stage that union ONCE into LDS (28 KB: P as 4 class-pair float2 planes
// + f plane) with coalesced global loads, then the inner loop reads the DS
// pipe instead of issuing scattered L1 line-gathers (f: 16 lines/inst,
// P float4: ~21 lines/inst). Class-pair float2 layout keeps both staging
// writes and in-loop ds_read_b64 at <=2-way bank aliasing (free).
__global__ __launch_bounds__(512) void sncut_rows(const float* __restrict__ f,
                                                  const float* __restrict__ P,
                                                  float* __restrict__ partials)
{
    __shared__ float2 Pl[4][NCELL];    // [class pair][cell] -> (P[c][2t], P[c][2t+1])
    __shared__ float  fl[NCELL];
    __shared__ float  sh[ROWS_PB][16];

    const int tid  = threadIdx.x;
    const int lane = tid & 63;
    const int wave = tid >> 6;
    const int i0   = blockIdx.x * ROWS_PB;

    const int zi0 = i0 & 31;           // in {0,8,16,24}
    const int yi  = (i0 >> 5) & 31;    // same for all 8 rows of the block
    const int xi  = i0 >> 10;          // same for all 8 rows of the block

    int Y0 = yi - 3;  Y0 = Y0 < 0 ? 0 : (Y0 > 25 ? 25 : Y0);
    int X0 = xi - 3;  X0 = X0 < 0 ? 0 : (X0 > 1 ? 1 : X0);
    int Z0 = zi0 - 4; Z0 = Z0 < 0 ? 0 : (Z0 > 16 ? 16 : Z0);
    // [Z0, Z0+15] covers every row's clamped 9-wide z-window (verified for
    // zi0 = 0/8/16/24: row z0 = clamp(zi-4,0,23), z0+8 <= Z0+15 always).

    // ---- stage the block's window into LDS (coalesced: z runs of 16 cells)
    for (int c = tid; c < NCELL; c += 512) {
        const int xc = c / 112;            // 112 = 7y * 16z
        const int r  = c - xc * 112;
        const int yc = r >> 4;
        const int zc = r & 15;
        const int j  = ((X0 + xc) << 10) + ((Y0 + yc) << 5) + (Z0 + zc);
        const float4 p0 = *reinterpret_cast<const float4*>(P + (size_t)j * NCLS);
        const float4 p1 = *reinterpret_cast<const float4*>(P + (size_t)j * NCLS + 4);
        Pl[0][c] = make_float2(p0.x, p0.y);
        Pl[1][c] = make_float2(p0.z, p0.w);
        Pl[2][c] = make_float2(p1.x, p1.y);
        Pl[3][c] = make_float2(p1.z, p1.w);
        fl[c]    = f[j];
    }
    __syncthreads();

    const int   i  = i0 + wave;
    const int   zi = zi0 + wave;       // i & 31, since zi0+7 <= 31
    const float fi = f[i];

    float v0 = 0.f, v1 = 0.f, v2 = 0.f, v3 = 0.f;
    float v4 = 0.f, v5 = 0.f, v6 = 0.f, v7 = 0.f;
    float vr = 0.f;

    if (lane < 63) {
        const int oy = lane / 9, oz = lane - oy * 9;   // 7 x 9 = 63 lanes

        int z0 = zi - 4; z0 = z0 < 0 ? 0 : (z0 > 23 ? 23 : z0);

        const int dy = yi - (Y0 + oy);
        const int dz = zi - (z0 + oz);
        const float base = (float)(dy * dy + dz * dz);
        const int cb = oy * 16 + (z0 - Z0) + oz;       // LDS cell at k=0

        #pragma unroll
        for (int k = 0; k < 7; ++k) {
            const int dx = xi - (X0 + k);
            const int c  = cb + k * 112;
            const float df  = fi - fl[c];
            const float arg = df * df * (1.0f / 9.0f) + (base + (float)(dx * dx));
            const float w   = __expf(-arg);
            const float2 a  = Pl[0][c];
            const float2 b  = Pl[1][c];
            const float2 cc = Pl[2][c];
            const float2 d  = Pl[3][c];
            v0 += w * a.x;  v1 += w * a.y;  v2 += w * b.x;  v3 += w * b.y;
            v4 += w * cc.x; v5 += w * cc.y; v6 += w * d.x;  v7 += w * d.y;
            vr += w;
        }
    }

    // ---- wave reduction (result lands in lane 0)
    float vals[9] = {v0, v1, v2, v3, v4, v5, v6, v7, vr};
    #pragma unroll
    for (int v = 0; v < 9; ++v) {
        float x = vals[v];
        #pragma unroll
        for (int off = 32; off > 0; off >>= 1)
            x += __shfl_down(x, off, 64);
        vals[v] = x;
    }

    // ---- per-row 16-entry contribution into LDS, fold 8 waves, one store
    if (lane == 0) {
        const float4 p0 = *reinterpret_cast<const float4*>(P + (size_t)i * NCLS);
        const float4 p1 = *reinterpret_cast<const float4*>(P + (size_t)i * NCLS + 4);
        sh[wave][0]  = p0.x * vals[0];
        sh[wave][1]  = p0.y * vals[1];
        sh[wave][2]  = p0.z * vals[2];
        sh[wave][3]  = p0.w * vals[3];
        sh[wave][4]  = p1.x * vals[4];
        sh[wave][5]  = p1.y * vals[5];
        sh[wave][6]  = p1.z * vals[6];
        sh[wave][7]  = p1.w * vals[7];
        sh[wave][8]  = p0.x * vals[8];
        sh[wave][9]  = p0.y * vals[8];
        sh[wave][10] = p0.z * vals[8];
        sh[wave][11] = p0.w * vals[8];
        sh[wave][12] = p1.x * vals[8];
        sh[wave][13] = p1.y * vals[8];
        sh[wave][14] = p1.z * vals[8];
        sh[wave][15] = p1.w * vals[8];
    }
    __syncthreads();
    if (tid < 16) {
        float s = 0.f;
        #pragma unroll
        for (int wv = 0; wv < ROWS_PB; ++wv) s += sh[wv][tid];
        partials[(size_t)blockIdx.x * 16 + tid] = s;
    }
}

// Fold 1024 x 16 partials -> 16 sums -> scalar loss. 1024 threads:
// thread (g = tid>>4 in [0,64), e = tid&15) sums 16 strided entries
// (independent loads, latency hidden), LDS combine across groups.
__global__ __launch_bounds__(1024) void sncut_final(const float* __restrict__ partials,
                                                    float* __restrict__ out)
{
    const int tid = threadIdx.x;
    const int e = tid & 15;
    const int g = tid >> 4;        // 0..63

    float s = 0.f;
    #pragma unroll
    for (int m = 0; m < GRID / 64; ++m)        // 16 iterations
        s += partials[(size_t)(g + m * 64) * 16 + e];

    __shared__ float acc[64][17];
    acc[g][e] = s;
    __syncthreads();

    __shared__ float sums[16];
    if (tid < 16) {
        float t = 0.f;
        #pragma unroll
        for (int g2 = 0; g2 < 64; ++g2) t += acc[g2][tid];
        sums[tid] = t;
    }
    __syncthreads();
    if (tid == 0) {
        float loss = (float)NCLS;
        #pragma unroll
        for (int t = 0; t < NCLS; ++t) loss -= sums[t] / sums[NCLS + t];
        out[0] = loss;
    }
}

extern "C" void kernel_launch(void* const* d_in, const int* in_sizes, int n_in,
                              void* d_out, int out_size, void* d_ws, size_t ws_size,
                              hipStream_t stream) {
    const float* f = (const float*)d_in[0];   // patch, 8192 fp32
    const float* P = (const float*)d_in[1];   // prob, 8192x8 fp32
    // d_in[2] is k==8 (compile-time constant here)

    float* partials = (float*)d_ws;           // GRID*16 floats = 64 KB, fully overwritten

    sncut_rows<<<GRID, 512, 0, stream>>>(f, P, partials);
    sncut_final<<<1, 1024, 0, stream>>>(partials, (float*)d_out);
}